// Round 2
// baseline (407.297 us; speedup 1.0000x reference)
//
#include <hip/hip_runtime.h>

// Problem constants (from reference)
constexpr int B    = 16384;
constexpr int F    = 30;
constexpr int BINS = 30;
constexpr int EMB  = 100;
constexpr float T  = 0.5f;
constexpr int PAIRS = B * F;           // 491520
constexpr int BLOCK = 256;             // 491520 / 256 = 1920 exact

// Round 2: weights are wave-uniform -> read them straight from global with
// lane-invariant indices so the compiler emits s_load into SGPRs (scalar
// cache, separate issue pipe). Round 1 was LDS-instruction-issue bound:
// ~3900 broadcast ds_read_b32 per wave serialized the whole kernel at
// VALUBusy=26%. No LDS at all in this version.
__global__ __launch_bounds__(BLOCK) void ad_embed_kernel(
    const float* __restrict__ x,   // [B*F]
    const float* __restrict__ W1,  // [BINS]
    const float* __restrict__ Wl,  // [BINS*BINS] row-major (o,i)
    const float* __restrict__ W2,  // [EMB*BINS]  row-major (o,i)
    float* __restrict__ out)       // [PAIRS*EMB]
{
    const int pair = blockIdx.x * BLOCK + threadIdx.x;   // grid exact, no guard
    const float xv = x[pair];                            // coalesced 4B/lane

    // y_i = leaky_relu(x * W1[i]); W1 index uniform -> s_load
    float y[BINS];
#pragma unroll
    for (int i = 0; i < BINS; ++i) {
        float v = xv * W1[i];
        y[i] = fmaxf(v, 0.01f * v);
    }

    // z_o = (sum_i y_i * Wl[o,i] + 0.1*y_o) * T ; track max for softmax.
    // Wl index is compile-time-constant after unroll -> batched s_load_dwordxN.
    float z[BINS];
    float m = -INFINITY;
#pragma unroll
    for (int o = 0; o < BINS; ++o) {
        float acc = 0.1f * y[o];
#pragma unroll
        for (int i = 0; i < BINS; ++i)
            acc = fmaf(y[i], Wl[o * BINS + i], acc);   // SGPR operand FMA
        float zo = acc * T;
        z[o] = zo;
        m = fmaxf(m, zo);
    }

    // softmax over 30 bins
    float sum = 0.f;
#pragma unroll
    for (int o = 0; o < BINS; ++o) {
        float e = __expf(z[o] - m);
        z[o] = e;
        sum += e;
    }
    const float inv = 1.0f / sum;
#pragma unroll
    for (int o = 0; o < BINS; ++o) z[o] *= inv;

    // out_o = sum_i p_i * W2[o,i]; W2 index uniform (o is a uniform loop
    // counter) -> s_load with SGPR offset. float4 stores, 400 B/thread.
    float* op = out + (size_t)pair * EMB;
    for (int o = 0; o < EMB; o += 4) {          // rolled x25 to bound code size
        float a0 = 0.f, a1 = 0.f, a2 = 0.f, a3 = 0.f;
#pragma unroll
        for (int i = 0; i < BINS; ++i) {
            const float p = z[i];
            a0 = fmaf(p, W2[(o + 0) * BINS + i], a0);
            a1 = fmaf(p, W2[(o + 1) * BINS + i], a1);
            a2 = fmaf(p, W2[(o + 2) * BINS + i], a2);
            a3 = fmaf(p, W2[(o + 3) * BINS + i], a3);
        }
        float4 r; r.x = a0; r.y = a1; r.z = a2; r.w = a3;
        *reinterpret_cast<float4*>(op + o) = r;
    }
}

extern "C" void kernel_launch(void* const* d_in, const int* in_sizes, int n_in,
                              void* d_out, int out_size, void* d_ws, size_t ws_size,
                              hipStream_t stream) {
    const float* x  = (const float*)d_in[0];
    const float* W1 = (const float*)d_in[1];
    const float* Wl = (const float*)d_in[2];
    const float* W2 = (const float*)d_in[3];
    float* out = (float*)d_out;

    dim3 grid(PAIRS / BLOCK);   // 1920
    dim3 block(BLOCK);
    ad_embed_kernel<<<grid, block, 0, stream>>>(x, W1, Wl, W2, out);
}

// Round 3
// 267.700 us; speedup vs baseline: 1.5215x; 1.5215x over previous
//
#include <hip/hip_runtime.h>

// Problem constants (from reference)
constexpr int B    = 16384;
constexpr int F    = 30;
constexpr int BINS = 30;
constexpr int EMB  = 100;
constexpr float T  = 0.5f;
constexpr int PAIRS = B * F;           // 491520
constexpr int BLOCK = 256;             // exact: 491520 / 256 = 1920 blocks
constexpr int WPB   = BLOCK / 64;      // 4 waves per block
constexpr int GRP   = 16;              // rows staged per drain group
constexpr int CHUNKS = EMB / 4;        // 25 float4 per output row

// Round 3: round 2 was write-path bound (WRITE_SIZE 535 MB vs 197 MB payload,
// ~2 TB/s effective: per-thread 400B row stores scatter 16B chunks across
// lines -> partial-line HBM writes). Fix: hold the row in registers, transpose
// 16 rows at a time through a per-wave LDS buffer, drain with fully
// contiguous 1024B-per-instruction wave stores (complete 128B lines).
// Weights stay on the scalar path (SGPR operands, separate pipe).
__global__ __launch_bounds__(BLOCK) void ad_embed_kernel(
    const float* __restrict__ x,   // [B*F]
    const float* __restrict__ W1,  // [BINS]
    const float* __restrict__ Wl,  // [BINS*BINS] row-major (o,i)
    const float* __restrict__ W2,  // [EMB*BINS]  row-major (o,i)
    float* __restrict__ out)       // [PAIRS*EMB]
{
    __shared__ float4 sbuf[WPB][GRP][CHUNKS];   // 4*16*25*16 = 25.6 KB

    const int tid  = threadIdx.x;
    const int wave = tid >> 6;
    const int lane = tid & 63;
    const int pair = blockIdx.x * BLOCK + tid;   // grid exact, no guard
    const float xv = x[pair];                    // coalesced 4B/lane

    // y_i = leaky_relu(x * W1[i])  (slope 0.01)
    float y[BINS];
#pragma unroll
    for (int i = 0; i < BINS; ++i) {
        float v = xv * W1[i];
        y[i] = fmaxf(v, 0.01f * v);
    }

    // z_o = (sum_i y_i * Wl[o,i] + 0.1*y_o) * T ; track max
    float z[BINS];
    float m = -INFINITY;
#pragma unroll
    for (int o = 0; o < BINS; ++o) {
        float acc = 0.1f * y[o];
#pragma unroll
        for (int i = 0; i < BINS; ++i)
            acc = fmaf(y[i], Wl[o * BINS + i], acc);   // SGPR-operand FMA
        float zo = acc * T;
        z[o] = zo;
        m = fmaxf(m, zo);
    }

    // softmax over 30 bins
    float sum = 0.f;
#pragma unroll
    for (int o = 0; o < BINS; ++o) {
        float e = __expf(z[o] - m);
        z[o] = e;
        sum += e;
    }
    const float inv = 1.0f / sum;
#pragma unroll
    for (int o = 0; o < BINS; ++o) z[o] *= inv;

    // Full output row into registers: 25 x float4 (fully unrolled so rowv
    // stays in VGPRs — a rolled loop would force dynamic indexing/spill).
    float4 rowv[CHUNKS];
#pragma unroll
    for (int c = 0; c < CHUNKS; ++c) {
        float a0 = 0.f, a1 = 0.f, a2 = 0.f, a3 = 0.f;
#pragma unroll
        for (int i = 0; i < BINS; ++i) {
            const float p = z[i];
            a0 = fmaf(p, W2[(4 * c + 0) * BINS + i], a0);
            a1 = fmaf(p, W2[(4 * c + 1) * BINS + i], a1);
            a2 = fmaf(p, W2[(4 * c + 2) * BINS + i], a2);
            a3 = fmaf(p, W2[(4 * c + 3) * BINS + i], a3);
        }
        rowv[c] = make_float4(a0, a1, a2, a3);
    }

    // Drain: 4 groups of 16 rows via per-wave LDS transpose.
    // Staging write: lanes stride 25 float4 = 100 dwords -> 2-way bank alias
    // (free, m136). Drain read: consecutive float4 per lane (linear, max BW).
    // Drain store: 64 lanes x 16B contiguous = 1024B fully-covered lines.
    float4* out4 = reinterpret_cast<float4*>(out);
    const size_t waveBase = (size_t)(blockIdx.x * BLOCK + wave * 64);
    const int grp  = lane >> 4;
    const int slot = lane & 15;
#pragma unroll
    for (int g = 0; g < 4; ++g) {
        if (grp == g) {
#pragma unroll
            for (int c = 0; c < CHUNKS; ++c) sbuf[wave][slot][c] = rowv[c];
        }
        __syncthreads();
        const size_t gbase = (waveBase + (size_t)g * GRP) * CHUNKS; // float4 units
#pragma unroll
        for (int k = 0; k < 7; ++k) {
            int idx = k * 64 + lane;            // 0..447, valid < 400
            if (idx < GRP * CHUNKS) {
                out4[gbase + idx] = sbuf[wave][idx / CHUNKS][idx % CHUNKS];
            }
        }
        __syncthreads();
    }
}

extern "C" void kernel_launch(void* const* d_in, const int* in_sizes, int n_in,
                              void* d_out, int out_size, void* d_ws, size_t ws_size,
                              hipStream_t stream) {
    const float* x  = (const float*)d_in[0];
    const float* W1 = (const float*)d_in[1];
    const float* Wl = (const float*)d_in[2];
    const float* W2 = (const float*)d_in[3];
    float* out = (float*)d_out;

    dim3 grid(PAIRS / BLOCK);   // 1920
    dim3 block(BLOCK);
    ad_embed_kernel<<<grid, block, 0, stream>>>(x, W1, Wl, W2, out);
}